// Round 6
// baseline (938.067 us; speedup 1.0000x reference)
//
#include <hip/hip_runtime.h>
#include <hip/hip_bf16.h>
#include <cmath>

// MatchingNet round 8: ATTRIBUTION build on the R7 structure (outputs bit-identical).
//  * expP_gemm repeated x5 in-kernel (idempotent: P stores rewrite same values,
//    atomicMax monotone; extra __syncthreads per rep prevents tile WAR race).
//  * final repeated x4 in-kernel (pure recompute + rewrite).
//  * Their dispatch durations (5G, 4F) will appear in the rocprof top-5 next to
//    the ~210us poison fills -> exact per-kernel cost. smalls = dur_base - F - G.
//  * Everything else verbatim R7 (Taylor Sinkhorn chain, validated).

#define LDIM 3600
#define DDIM 256
#define BDIM 2
#define VS   3604      // per-batch vector stride (floats), 16B-aligned
#define AGGS 260       // per-batch aggregate block: [0]=S, [1]=bin, [2..257]=t

#define REP_GEMM 5
#define REP_FINAL 4

typedef __attribute__((ext_vector_type(8))) short    bf16x8;
typedef __attribute__((ext_vector_type(4))) float    f32x4;
typedef __attribute__((ext_vector_type(8))) _Float16 h8;
typedef __attribute__((ext_vector_type(4))) _Float16 h4v;

__device__ __forceinline__ short f2bf(float f) {
    unsigned u = __float_as_uint(f);
    u += 0x7fffu + ((u >> 16) & 1u);   // RNE
    return (short)(u >> 16);
}
__device__ __forceinline__ float bf2f(short s) {
    return __uint_as_float(((unsigned)(unsigned short)s) << 16);
}

// ---- input fp32 -> bf16 conversion ----
__global__ __launch_bounds__(256) void convert_kernel(
    const float4* __restrict__ m0, const float4* __restrict__ m1,
    short4* __restrict__ q, short4* __restrict__ r)
{
    int i = blockIdx.x * 256 + threadIdx.x;   // 460800 float4 per tensor
    float4 a = m0[i]; float4 b = m1[i];
    short4 qa, rb;
    qa.x = f2bf(a.x); qa.y = f2bf(a.y); qa.z = f2bf(a.z); qa.w = f2bf(a.w);
    rb.x = f2bf(b.x); rb.y = f2bf(b.y); rb.z = f2bf(b.z); rb.w = f2bf(b.w);
    q[i] = qa; r[i] = rb;
}

// ---- column sums: sQ[d] = sum_i q[i][d], sR[d] = sum_j r[j][d] ----
__global__ __launch_bounds__(256) void sums_kernel(
    const short* __restrict__ Qb, const short* __restrict__ Rb,
    float* __restrict__ sQ, float* __restrict__ sR)
{
    const int batch = blockIdx.y;
    const short* M = (blockIdx.z == 0 ? Qb : Rb) + (size_t)batch * LDIM * DDIM;
    float* out = (blockIdx.z == 0 ? sQ : sR) + batch * 256;
    __shared__ float tsh[256];
    const int tid = threadIdx.x, wave = tid >> 6, lane = tid & 63;
    tsh[tid] = 0.f; __syncthreads();
    float a0 = 0.f, a1 = 0.f, a2 = 0.f, a3 = 0.f;
    const int r0 = blockIdx.x * 64 + wave * 16;
    for (int k = 0; k < 16; k++) {
        int r = r0 + k;
        if (r < LDIM) {
            short4 v = *(const short4*)(M + (size_t)r * DDIM + lane * 4);
            a0 += bf2f(v.x); a1 += bf2f(v.y); a2 += bf2f(v.z); a3 += bf2f(v.w);
        }
    }
    atomicAdd(&tsh[lane * 4 + 0], a0); atomicAdd(&tsh[lane * 4 + 1], a1);
    atomicAdd(&tsh[lane * 4 + 2], a2); atomicAdd(&tsh[lane * 4 + 3], a3);
    __syncthreads();
    atomicAdd(out + tid, tsh[tid]);
}

// ---- Taylor Rv_i = 3600 + q_i.sR/6553.6 ; Cv_j = 3600 + r_j.sQ/6553.6 ----
__global__ __launch_bounds__(256) void rvcv_kernel(
    const short* __restrict__ Qb, const short* __restrict__ Rb,
    const float* __restrict__ sQ, const float* __restrict__ sR,
    float* __restrict__ Rv, float* __restrict__ Cv)
{
    const int batch = blockIdx.y;
    const short* M = (blockIdx.z == 0 ? Qb : Rb) + (size_t)batch * LDIM * DDIM;
    const float* sv = (blockIdx.z == 0 ? sR : sQ) + batch * 256;
    float* out = (blockIdx.z == 0 ? Rv : Cv) + batch * VS;
    const int tid = threadIdx.x, wave = tid >> 6, lane = tid & 63;
    const float s0 = sv[lane * 4], s1 = sv[lane * 4 + 1];
    const float s2 = sv[lane * 4 + 2], s3 = sv[lane * 4 + 3];
    const int r0 = blockIdx.x * 64 + wave * 16;
    for (int k = 0; k < 16; k++) {
        int r = r0 + k;
        if (r >= LDIM) break;
        short4 v = *(const short4*)(M + (size_t)r * DDIM + lane * 4);
        float d = bf2f(v.x) * s0 + bf2f(v.y) * s1 + bf2f(v.z) * s2 + bf2f(v.w) * s3;
#pragma unroll
        for (int off = 32; off; off >>= 1) d += __shfl_xor(d, off, 64);
        if (lane == 0) out[r] = 3600.0f + d * (1.0f / 6553.6f);
    }
}

// ---- generic Sinkhorn half-step (Taylor, exp domain) — verbatim R6 ----
__global__ __launch_bounds__(256) void agg_kernel(
    const short* __restrict__ Mb, const float* __restrict__ in_rv,
    const float* __restrict__ aggIn, float* __restrict__ aggOut,
    float* __restrict__ vecOut, const float* __restrict__ alpha_p,
    float scale)
{
    const int batch = blockIdx.y, tid = threadIdx.x;
    const int wave = tid >> 6, lane = tid & 63;
    const short* M = Mb + (size_t)batch * LDIM * DDIM;
    const float alpha = alpha_p[0];
    const float ea = __expf(alpha);
    __shared__ float tin_sh[256];
    __shared__ float tsh[256];
    __shared__ float ssh;
    float Sin = 0.f, binin = 0.f;
    if (in_rv == nullptr) {
        const float* gi = aggIn + batch * AGGS;
        Sin = gi[0]; binin = gi[1];
        tin_sh[tid] = gi[2 + tid];
    } else tin_sh[tid] = 0.f;
    if (tid == 0) ssh = 0.f;
    tsh[tid] = 0.f;
    __syncthreads();
    const float t0 = tin_sh[lane * 4], t1 = tin_sh[lane * 4 + 1];
    const float t2 = tin_sh[lane * 4 + 2], t3 = tin_sh[lane * 4 + 3];
    float a0 = 0.f, a1 = 0.f, a2 = 0.f, a3 = 0.f, sacc = 0.f;
    const int r0 = blockIdx.x * 64 + wave * 16;
    for (int k = 0; k < 16; k++) {
        int r = r0 + k;
        if (r >= LDIM) break;
        short4 v = *(const short4*)(M + (size_t)r * DDIM + lane * 4);
        float m0 = bf2f(v.x), m1 = bf2f(v.y), m2 = bf2f(v.z), m3 = bf2f(v.w);
        float denom;
        if (in_rv) {
            denom = in_rv[batch * VS + r] + ea;   // bin_in = 1
        } else {
            float d = m0 * t0 + m1 * t1 + m2 * t2 + m3 * t3;
#pragma unroll
            for (int off = 32; off; off >>= 1) d += __shfl_xor(d, off, 64);
            denom = Sin + d * (1.0f / 6553.6f) + ea * binin;
        }
        float a = scale / denom;
        if (vecOut && lane == 0) vecOut[batch * VS + r] = a;
        if (aggOut) {
            a0 += a * m0; a1 += a * m1; a2 += a * m2; a3 += a * m3;
            if (lane == 0) sacc += a;
        }
    }
    if (aggOut) {
        atomicAdd(&tsh[lane * 4 + 0], a0); atomicAdd(&tsh[lane * 4 + 1], a1);
        atomicAdd(&tsh[lane * 4 + 2], a2); atomicAdd(&tsh[lane * 4 + 3], a3);
        if (lane == 0) atomicAdd(&ssh, sacc);
        __syncthreads();
        float* go = aggOut + batch * AGGS;
        atomicAdd(go + 2 + tid, tsh[tid]);
        if (tid == 0) atomicAdd(go + 0, ssh);
        if (blockIdx.x == 0 && tid == 0) {
            float denb = in_rv ? 3601.0f
                               : (aggIn[batch * AGGS + 0] + aggIn[batch * AGGS + 1]);
            go[1] = 0.5f * __expf(-alpha) / denb;   // next bin = (n/(m+n))e^-a/(S+bin)
        }
    }
}

// ---- ONE GEMM: fp16 P (LDS-coalesced h8 stores) + rowM/colM maxes of cm ----
// ATTRIBUTION: body repeated REP_GEMM times (idempotent). Dispatch dur = 5G.
__global__ __launch_bounds__(256) void expP_gemm_kernel(
    const short* __restrict__ Xb, const short* __restrict__ Yb,
    const float* __restrict__ Rv, const float* __restrict__ Cv,
    _Float16* __restrict__ Pout, float* __restrict__ rowM, float* __restrict__ colM)
{
    __shared__ __align__(16) _Float16 tile[128][136];   // 272B row = 16B-aligned
    const int batch = blockIdx.z;
    const short* X = Xb + (size_t)batch * LDIM * DDIM;
    const short* Y = Yb + (size_t)batch * LDIM * DDIM;
    _Float16* Pb = Pout + (size_t)batch * LDIM * LDIM;

    const int wave = threadIdx.x >> 6, lane = threadIdx.x & 63;
    const int wm = wave >> 1, wn = wave & 1;
    const int bm0 = blockIdx.y * 128 + wm * 64;
    const int bn0 = blockIdx.x * 128 + wn * 64;
    const int l16 = lane & 15, quad = lane >> 4;

    for (int rep = 0; rep < REP_GEMM; rep++) {
    f32x4 acc[4][4];
#pragma unroll
    for (int s = 0; s < 4; s++)
#pragma unroll
        for (int t = 0; t < 4; t++) acc[s][t] = (f32x4){0.f, 0.f, 0.f, 0.f};
    const short* xr[4]; const short* yr[4];
#pragma unroll
    for (int s = 0; s < 4; s++) {
        int r = bm0 + s * 16 + l16; r = r < LDIM ? r : LDIM - 1;
        xr[s] = X + (size_t)r * DDIM;
        int c = bn0 + s * 16 + l16; c = c < LDIM ? c : LDIM - 1;
        yr[s] = Y + (size_t)c * DDIM;
    }
    for (int k0 = 0; k0 < DDIM; k0 += 32) {
        const int kk = k0 + quad * 8;
        bf16x8 af[4], bfr[4];
#pragma unroll
        for (int s = 0; s < 4; s++) {
            af[s]  = *(const bf16x8*)(xr[s] + kk);
            bfr[s] = *(const bf16x8*)(yr[s] + kk);
        }
#pragma unroll
        for (int s = 0; s < 4; s++)
#pragma unroll
            for (int t = 0; t < 4; t++)
                acc[s][t] = __builtin_amdgcn_mfma_f32_16x16x32_bf16(af[s], bfr[t], acc[s][t], 0, 0, 0);
    }

    const float inv = 1.0f / 6553.6f;
    float rv_s[4][4];
#pragma unroll
    for (int s = 0; s < 4; s++)
#pragma unroll
        for (int r = 0; r < 4; r++) {
            int row = bm0 + s * 16 + quad * 4 + r;
            rv_s[s][r] = Rv[batch * VS + (row < LDIM ? row : LDIM - 1)];
        }
    float rmax[4][4];
#pragma unroll
    for (int s = 0; s < 4; s++)
#pragma unroll
        for (int r = 0; r < 4; r++) rmax[s][r] = 0.f;

#pragma unroll
    for (int t = 0; t < 4; t++) {
        const int col = bn0 + t * 16 + l16;     // D: col=lane&15, row=quad*4+reg
        const bool colok = col < LDIM;
        const int lc = wn * 64 + t * 16 + l16;
        const float cvt = Cv[batch * VS + (colok ? col : LDIM - 1)];
        float cmax = 0.f;
#pragma unroll
        for (int s = 0; s < 4; s++) {
            const int row0 = bm0 + s * 16 + quad * 4;
            const bool rowok = row0 < LDIM;
            const int lr0 = wm * 64 + s * 16 + quad * 4;
#pragma unroll
            for (int r = 0; r < 4; r++) {
                _Float16 ph = (_Float16)__expf(acc[s][t][r] * inv);
                tile[lr0 + r][lc] = ph;
                float pf = (float)ph;
                float cmv = (pf * pf) / (rv_s[s][r] * cvt);  // IDENTICAL expr to final
                cmv = (rowok && colok) ? cmv : 0.f;
                rmax[s][r] = fmaxf(rmax[s][r], cmv);
                cmax = fmaxf(cmax, cmv);
            }
        }
        cmax = fmaxf(cmax, __shfl_xor(cmax, 16, 64));
        cmax = fmaxf(cmax, __shfl_xor(cmax, 32, 64));
        if (quad == 0 && colok)
            atomicMax((unsigned*)(colM + batch * VS + col), __float_as_uint(cmax));
    }
#pragma unroll
    for (int s = 0; s < 4; s++)
#pragma unroll
        for (int r = 0; r < 4; r++) {
            float v = rmax[s][r];
            v = fmaxf(v, __shfl_xor(v, 1, 64));
            v = fmaxf(v, __shfl_xor(v, 2, 64));
            v = fmaxf(v, __shfl_xor(v, 4, 64));
            v = fmaxf(v, __shfl_xor(v, 8, 64));
            int row = bm0 + s * 16 + quad * 4 + r;
            if (l16 == 0 && row < LDIM)
                atomicMax((unsigned*)(rowM + batch * VS + row), __float_as_uint(v));
        }
    __syncthreads();
    // coalesced P store: 8 rounds x (16 rows x 16 chunks of 16B) = 1KB/wave-instr
    const int srow = threadIdx.x >> 4;     // 0..15
    const int schunk = threadIdx.x & 15;   // 16B chunk within the 128-col tile
    const int gcol = blockIdx.x * 128 + schunk * 8;
#pragma unroll
    for (int rd = 0; rd < 8; rd++) {
        const int lr = rd * 16 + srow;
        const int grow = blockIdx.y * 128 + lr;
        if (grow < LDIM && gcol < LDIM)
            *(h8*)(Pb + (size_t)grow * LDIM + gcol) = *(const h8*)&tile[lr][schunk * 8];
    }
    __syncthreads();   // rep r+1's tile writes must not race rep r's reads
    }
}

// ---- final: pure elementwise, block per row, float4 streaming stores ----
// ATTRIBUTION: body repeated REP_FINAL times (idempotent). Dispatch dur = 4F.
__global__ __launch_bounds__(256) void final_kernel(
    const _Float16* __restrict__ P, const float* __restrict__ bv,
    const float* __restrict__ Rvec, const float* __restrict__ Cvec,
    const float* __restrict__ rowM, const float* __restrict__ colM,
    const float* __restrict__ av3, float* __restrict__ out)
{
    const int batch = blockIdx.y, row = blockIdx.x, tid = threadIdx.x;
    const h4v* prow = (const h4v*)(P + ((size_t)batch * LDIM + row) * LDIM);
    const float4* b4 = (const float4*)(bv + batch * VS);
    const float4* c4 = (const float4*)(Cvec + batch * VS);
    const float4* m4 = (const float4*)(colM + batch * VS);
    const float Rr = Rvec[batch * VS + row];
    const float rM = rowM[batch * VS + row];
    const float as = av3[batch * VS + row];

    const size_t PLANE = (size_t)BDIM * LDIM * LDIM;
    const size_t base = ((size_t)batch * LDIM + row) * LDIM;
    for (int rep = 0; rep < REP_FINAL; rep++) {
    for (int jv = tid; jv < 900; jv += 256) {
        h4v hv = prow[jv]; float4 b = b4[jv]; float4 c = c4[jv]; float4 cM = m4[jv];
        float4 cmv, cfv, skv;
        {
            float p = (float)hv[0]; float cm = (p * p) / (Rr * c.x);
            cmv.x = cm; cfv.x = (cm == rM && cm == cM.x) ? cm : 0.f; skv.x = p * as * b.x;
        }
        {
            float p = (float)hv[1]; float cm = (p * p) / (Rr * c.y);
            cmv.y = cm; cfv.y = (cm == rM && cm == cM.y) ? cm : 0.f; skv.y = p * as * b.y;
        }
        {
            float p = (float)hv[2]; float cm = (p * p) / (Rr * c.z);
            cmv.z = cm; cfv.z = (cm == rM && cm == cM.z) ? cm : 0.f; skv.z = p * as * b.z;
        }
        {
            float p = (float)hv[3]; float cm = (p * p) / (Rr * c.w);
            cmv.w = cm; cfv.w = (cm == rM && cm == cM.w) ? cm : 0.f; skv.w = p * as * b.w;
        }
        *(float4*)(out + base + jv * 4) = cmv;
        *(float4*)(out + PLANE + base + jv * 4) = cfv;
        *(float4*)(out + 2 * PLANE + base + jv * 4) = skv;
    }
    }
}

extern "C" void kernel_launch(void* const* d_in, const int* in_sizes, int n_in,
                              void* d_out, int out_size, void* d_ws, size_t ws_size,
                              hipStream_t stream)
{
    const float* m0 = (const float*)d_in[0];
    const float* m1 = (const float*)d_in[1];
    const float* alpha = (const float*)d_in[2];
    float* out = (float*)d_out;
    char* ws = (char*)d_ws;

    // ws layout: bf16 inputs + fp16 P + small vectors (~59.4 MB total)
    short* Qb = (short*)(ws);                       // 3,686,400 B
    short* Rb = (short*)(ws + 3686400);             // 3,686,400 B
    _Float16* P = (_Float16*)(ws + 7372800);        // 51,840,000 B
    float* vec  = (float*)(ws + 59212800);
    float* Rv   = vec;                              // Taylor row sums   [2*VS]
    float* Cv   = vec + 2 * VS;                     // Taylor col sums   [2*VS]
    float* rowM = vec + 4 * VS;                     // row max of cm     [2*VS] (zeroed)
    float* colM = vec + 6 * VS;                     // col max of cm     [2*VS] (zeroed)
    float* sQ   = vec + 8 * VS;                     // [2*256] (zeroed)
    float* sR   = sQ + 512;                         // [2*256] (zeroed)
    float* G1   = sQ + 1024;                        // agg blocks [2*AGGS] each (zeroed)
    float* G2   = G1 + 2 * AGGS;
    float* G3   = G2 + 2 * AGGS;
    float* G4   = G3 + 2 * AGGS;
    float* bv   = G4 + 2 * AGGS;                    // exp(v2)           [2*VS]
    float* av3  = bv + 2 * VS;                      // as = 1/denom(u3)  [2*VS]

    const float CNORM = 1.0f / 7200.0f;

    // zero: rowM, colM, sQ, sR, G1..G4
    hipMemsetAsync(rowM, 0, (4 * VS + 1024 + 8 * AGGS) * sizeof(float), stream);
    convert_kernel<<<1800, 256, 0, stream>>>((const float4*)m0, (const float4*)m1,
                                             (short4*)Qb, (short4*)Rb);
    sums_kernel<<<dim3(57, 2, 2), 256, 0, stream>>>(Qb, Rb, sQ, sR);
    rvcv_kernel<<<dim3(57, 2, 2), 256, 0, stream>>>(Qb, Rb, sQ, sR, Rv, Cv);
    expP_gemm_kernel<<<dim3(29, 29, 2), 256, 0, stream>>>(Qb, Rb, Rv, Cv, P, rowM, colM);

    // Sinkhorn T=3 via Taylor GEMV half-steps: u1,v1,u2,v2 aggregate; u3 -> av3 vec
    agg_kernel<<<dim3(57, 2), 256, 0, stream>>>(Qb, Rv, nullptr, G1, nullptr, alpha, CNORM);
    agg_kernel<<<dim3(57, 2), 256, 0, stream>>>(Rb, nullptr, G1, G2, nullptr, alpha, CNORM);
    agg_kernel<<<dim3(57, 2), 256, 0, stream>>>(Qb, nullptr, G2, G3, nullptr, alpha, CNORM);
    agg_kernel<<<dim3(57, 2), 256, 0, stream>>>(Rb, nullptr, G3, G4, bv, alpha, CNORM);
    agg_kernel<<<dim3(57, 2), 256, 0, stream>>>(Qb, nullptr, G4, nullptr, av3, alpha, 1.0f);

    final_kernel<<<dim3(3600, 2), 256, 0, stream>>>(P, bv, Rv, Cv, rowM, colM, av3, out);
}

// Round 7
// 471.850 us; speedup vs baseline: 1.9881x; 1.9881x over previous
//
#include <hip/hip_runtime.h>
#include <hip/hip_bf16.h>
#include <cmath>

// MatchingNet round 9: dispatch-count collapse. R8 attribution: expP_gemm=71us,
// final=43us, smalls+gaps=411us (78% of runtime!). Fix: the Taylor aggregate
// chain is CLOSED-FORM (each step's t is a scalar multiple of sQ/sR; S_k,c_k,
// bin_k form a ~20-op scalar recurrence in W=sQ.sR/6553.6). Per-row outputs are
// elementwise in the Rv/Cv dots: bv_j=C/(E4+c3*dd_j), av3_i=1/(E5+c4*dd_i).
// Dropped terms <=6e-6 relative on aggregates -> <=1e-9 absolute on outputs
// (fp16-p floor is 9.5e-7). Pipeline: 5 nodes (was 11):
//   memset(4KB sQ/sR) -> convert+sums(atomics) -> vectors(dots->Rv,Cv,bv,av3;
//   zero rowM/colM; scalar chain per-block bitwise-identical) ->
//   expP_gemm (VERBATIM R7) -> final (VERBATIM R7).

#define LDIM 3600
#define DDIM 256
#define BDIM 2
#define VS   3604      // per-batch vector stride (floats), 16B-aligned

typedef __attribute__((ext_vector_type(8))) short    bf16x8;
typedef __attribute__((ext_vector_type(4))) float    f32x4;
typedef __attribute__((ext_vector_type(8))) _Float16 h8;
typedef __attribute__((ext_vector_type(4))) _Float16 h4v;

__device__ __forceinline__ short f2bf(float f) {
    unsigned u = __float_as_uint(f);
    u += 0x7fffu + ((u >> 16) & 1u);   // RNE
    return (short)(u >> 16);
}
__device__ __forceinline__ float bf2f(short s) {
    return __uint_as_float(((unsigned)(unsigned short)s) << 16);
}

// ---- fp32 -> bf16 conversion + fused column sums (atomics) ----
// grid 450: each thread converts 4 float4 of m0 and m1 (strided by 256 within
// the block's 1024-float4 span = 16 rows, single batch since 230400%1024==0).
__global__ __launch_bounds__(256) void convert_kernel(
    const float4* __restrict__ m0, const float4* __restrict__ m1,
    short4* __restrict__ q, short4* __restrict__ r,
    float* __restrict__ sQ, float* __restrict__ sR)
{
    __shared__ float sh[512];
    const int tid = threadIdx.x;
    sh[tid] = 0.f; sh[256 + tid] = 0.f;
    __syncthreads();
    float qa0 = 0.f, qa1 = 0.f, qa2 = 0.f, qa3 = 0.f;
    float ra0 = 0.f, ra1 = 0.f, ra2 = 0.f, ra3 = 0.f;
    const int base = blockIdx.x * 1024 + tid;
#pragma unroll
    for (int j = 0; j < 4; j++) {
        const int i = base + j * 256;
        float4 a = m0[i]; float4 b = m1[i];
        short4 qa, rb;
        qa.x = f2bf(a.x); qa.y = f2bf(a.y); qa.z = f2bf(a.z); qa.w = f2bf(a.w);
        rb.x = f2bf(b.x); rb.y = f2bf(b.y); rb.z = f2bf(b.z); rb.w = f2bf(b.w);
        q[i] = qa; r[i] = rb;
        qa0 += a.x; qa1 += a.y; qa2 += a.z; qa3 += a.w;
        ra0 += b.x; ra1 += b.y; ra2 += b.z; ra3 += b.w;
    }
    const int d0 = (tid & 63) * 4;   // float4-within-row is invariant across j
    atomicAdd(&sh[d0 + 0], qa0); atomicAdd(&sh[d0 + 1], qa1);
    atomicAdd(&sh[d0 + 2], qa2); atomicAdd(&sh[d0 + 3], qa3);
    atomicAdd(&sh[256 + d0 + 0], ra0); atomicAdd(&sh[256 + d0 + 1], ra1);
    atomicAdd(&sh[256 + d0 + 2], ra2); atomicAdd(&sh[256 + d0 + 3], ra3);
    __syncthreads();
    const int batch = blockIdx.x / 225;   // 225 blocks per batch
    atomicAdd(&sQ[batch * 256 + tid], sh[tid]);
    atomicAdd(&sR[batch * 256 + tid], sh[256 + tid]);
}

// ---- vectors: per-row dots -> Rv,Cv + closed-form Sinkhorn chain -> bv,av3 ----
// grid (57, 2, 2): x=64-row chunk, y=batch, z: 0 -> Q rows (Rv, av3, zero rowM),
//                                            1 -> R rows (Cv, bv, zero colM).
// Scalar chain computed identically (bitwise) in every block from sQ,sR,alpha.
__global__ __launch_bounds__(256) void vectors_kernel(
    const short* __restrict__ Qb, const short* __restrict__ Rb,
    const float* __restrict__ sQg, const float* __restrict__ sRg,
    const float* __restrict__ alpha_p,
    float* __restrict__ Rv, float* __restrict__ Cv,
    float* __restrict__ av3, float* __restrict__ bv,
    float* __restrict__ rowM, float* __restrict__ colM)
{
    const int batch = blockIdx.y, z = blockIdx.z;
    const int tid = threadIdx.x, wave = tid >> 6, lane = tid & 63;
    const short* M = (z ? Rb : Qb) + (size_t)batch * LDIM * DDIM;
    const float* sv = (z ? sQg : sRg) + batch * 256;   // dot target: other matrix's colsum

    // ---- W = sQ.sR via fixed-order block tree (deterministic, identical per block)
    __shared__ float red[256];
    __shared__ float sc[4];
    red[tid] = sQg[batch * 256 + tid] * sRg[batch * 256 + tid];
    __syncthreads();
    for (int w = 128; w; w >>= 1) {
        if (tid < w) red[tid] += red[tid + w];
        __syncthreads();
    }
    if (tid == 0) {
        const float alpha = alpha_p[0];
        const float ea = __expf(alpha), em = __expf(-alpha);
        const float C = 1.0f / 7200.0f;
        const float W = red[0] * (1.0f / 6553.6f);
        // u1: denom_i = D1 + dd_i, D1 = 3600 + ea
        const float D1 = 3600.0f + ea;
        const float S1 = (C / D1) * (3600.0f - W / D1);
        const float c1 = C / D1;
        const float bin1 = 0.5f * em / 3601.0f;
        // v1
        const float E2 = S1 + ea * bin1;
        const float S2 = (C / E2) * (3600.0f - c1 * W / E2);
        const float c2 = C / E2;
        const float bin2 = 0.5f * em / (S1 + bin1);
        // u2
        const float E3 = S2 + ea * bin2;
        const float S3 = (C / E3) * (3600.0f - c2 * W / E3);
        const float c3 = C / E3;
        const float bin3 = 0.5f * em / (S2 + bin2);
        // v2 (emits bv)
        const float E4 = S3 + ea * bin3;
        const float S4 = (C / E4) * (3600.0f - c3 * W / E4);
        const float c4 = C / E4;
        const float bin4 = 0.5f * em / (S3 + bin3);
        // u3 (emits av3)
        const float E5 = S4 + ea * bin4;
        sc[0] = E4; sc[1] = c3; sc[2] = E5; sc[3] = c4;
    }
    __syncthreads();
    const float E4 = sc[0], c3 = sc[1], E5 = sc[2], c4 = sc[3];
    const float C = 1.0f / 7200.0f;

    const float s0 = sv[lane * 4], s1 = sv[lane * 4 + 1];
    const float s2 = sv[lane * 4 + 2], s3 = sv[lane * 4 + 3];
    const int r0 = blockIdx.x * 64 + wave * 16;
    for (int k = 0; k < 16; k++) {
        const int r = r0 + k;
        if (r >= LDIM) break;
        short4 v = *(const short4*)(M + (size_t)r * DDIM + lane * 4);
        float d = bf2f(v.x) * s0 + bf2f(v.y) * s1 + bf2f(v.z) * s2 + bf2f(v.w) * s3;
#pragma unroll
        for (int off = 32; off; off >>= 1) d += __shfl_xor(d, off, 64);
        if (lane == 0) {
            const float dd = d * (1.0f / 6553.6f);
            if (z == 0) {
                Rv[batch * VS + r]   = 3600.0f + dd;
                av3[batch * VS + r]  = 1.0f / (E5 + c4 * dd);
                rowM[batch * VS + r] = 0.f;
            } else {
                Cv[batch * VS + r]   = 3600.0f + dd;
                bv[batch * VS + r]   = C / (E4 + c3 * dd);
                colM[batch * VS + r] = 0.f;
            }
        }
    }
}

// ---- ONE GEMM: fp16 P (LDS-coalesced h8 stores) + rowM/colM maxes of cm ----
// VERBATIM R7 (measured 71us). cm from the fp16-ROUNDED p: bit-identical to final.
__global__ __launch_bounds__(256) void expP_gemm_kernel(
    const short* __restrict__ Xb, const short* __restrict__ Yb,
    const float* __restrict__ Rv, const float* __restrict__ Cv,
    _Float16* __restrict__ Pout, float* __restrict__ rowM, float* __restrict__ colM)
{
    __shared__ __align__(16) _Float16 tile[128][136];   // 272B row = 16B-aligned
    const int batch = blockIdx.z;
    const short* X = Xb + (size_t)batch * LDIM * DDIM;
    const short* Y = Yb + (size_t)batch * LDIM * DDIM;
    _Float16* Pb = Pout + (size_t)batch * LDIM * LDIM;

    const int wave = threadIdx.x >> 6, lane = threadIdx.x & 63;
    const int wm = wave >> 1, wn = wave & 1;
    const int bm0 = blockIdx.y * 128 + wm * 64;
    const int bn0 = blockIdx.x * 128 + wn * 64;
    const int l16 = lane & 15, quad = lane >> 4;

    f32x4 acc[4][4];
#pragma unroll
    for (int s = 0; s < 4; s++)
#pragma unroll
        for (int t = 0; t < 4; t++) acc[s][t] = (f32x4){0.f, 0.f, 0.f, 0.f};
    const short* xr[4]; const short* yr[4];
#pragma unroll
    for (int s = 0; s < 4; s++) {
        int r = bm0 + s * 16 + l16; r = r < LDIM ? r : LDIM - 1;
        xr[s] = X + (size_t)r * DDIM;
        int c = bn0 + s * 16 + l16; c = c < LDIM ? c : LDIM - 1;
        yr[s] = Y + (size_t)c * DDIM;
    }
    for (int k0 = 0; k0 < DDIM; k0 += 32) {
        const int kk = k0 + quad * 8;
        bf16x8 af[4], bfr[4];
#pragma unroll
        for (int s = 0; s < 4; s++) {
            af[s]  = *(const bf16x8*)(xr[s] + kk);
            bfr[s] = *(const bf16x8*)(yr[s] + kk);
        }
#pragma unroll
        for (int s = 0; s < 4; s++)
#pragma unroll
            for (int t = 0; t < 4; t++)
                acc[s][t] = __builtin_amdgcn_mfma_f32_16x16x32_bf16(af[s], bfr[t], acc[s][t], 0, 0, 0);
    }

    const float inv = 1.0f / 6553.6f;
    float rv_s[4][4];
#pragma unroll
    for (int s = 0; s < 4; s++)
#pragma unroll
        for (int r = 0; r < 4; r++) {
            int row = bm0 + s * 16 + quad * 4 + r;
            rv_s[s][r] = Rv[batch * VS + (row < LDIM ? row : LDIM - 1)];
        }
    float rmax[4][4];
#pragma unroll
    for (int s = 0; s < 4; s++)
#pragma unroll
        for (int r = 0; r < 4; r++) rmax[s][r] = 0.f;

#pragma unroll
    for (int t = 0; t < 4; t++) {
        const int col = bn0 + t * 16 + l16;     // D: col=lane&15, row=quad*4+reg
        const bool colok = col < LDIM;
        const int lc = wn * 64 + t * 16 + l16;
        const float cvt = Cv[batch * VS + (colok ? col : LDIM - 1)];
        float cmax = 0.f;
#pragma unroll
        for (int s = 0; s < 4; s++) {
            const int row0 = bm0 + s * 16 + quad * 4;
            const bool rowok = row0 < LDIM;
            const int lr0 = wm * 64 + s * 16 + quad * 4;
#pragma unroll
            for (int r = 0; r < 4; r++) {
                _Float16 ph = (_Float16)__expf(acc[s][t][r] * inv);
                tile[lr0 + r][lc] = ph;
                float pf = (float)ph;
                float cmv = (pf * pf) / (rv_s[s][r] * cvt);  // IDENTICAL expr to final
                cmv = (rowok && colok) ? cmv : 0.f;
                rmax[s][r] = fmaxf(rmax[s][r], cmv);
                cmax = fmaxf(cmax, cmv);
            }
        }
        cmax = fmaxf(cmax, __shfl_xor(cmax, 16, 64));
        cmax = fmaxf(cmax, __shfl_xor(cmax, 32, 64));
        if (quad == 0 && colok)
            atomicMax((unsigned*)(colM + batch * VS + col), __float_as_uint(cmax));
    }
#pragma unroll
    for (int s = 0; s < 4; s++)
#pragma unroll
        for (int r = 0; r < 4; r++) {
            float v = rmax[s][r];
            v = fmaxf(v, __shfl_xor(v, 1, 64));
            v = fmaxf(v, __shfl_xor(v, 2, 64));
            v = fmaxf(v, __shfl_xor(v, 4, 64));
            v = fmaxf(v, __shfl_xor(v, 8, 64));
            int row = bm0 + s * 16 + quad * 4 + r;
            if (l16 == 0 && row < LDIM)
                atomicMax((unsigned*)(rowM + batch * VS + row), __float_as_uint(v));
        }
    __syncthreads();
    // coalesced P store: 8 rounds x (16 rows x 16 chunks of 16B) = 1KB/wave-instr
    const int srow = threadIdx.x >> 4;     // 0..15
    const int schunk = threadIdx.x & 15;   // 16B chunk within the 128-col tile
    const int gcol = blockIdx.x * 128 + schunk * 8;
#pragma unroll
    for (int rd = 0; rd < 8; rd++) {
        const int lr = rd * 16 + srow;
        const int grow = blockIdx.y * 128 + lr;
        if (grow < LDIM && gcol < LDIM)
            *(h8*)(Pb + (size_t)grow * LDIM + gcol) = *(const h8*)&tile[lr][schunk * 8];
    }
}

// ---- final: pure elementwise, block per row, float4 streaming stores ----
// VERBATIM R7 (measured 43us).
__global__ __launch_bounds__(256) void final_kernel(
    const _Float16* __restrict__ P, const float* __restrict__ bv,
    const float* __restrict__ Rvec, const float* __restrict__ Cvec,
    const float* __restrict__ rowM, const float* __restrict__ colM,
    const float* __restrict__ av3, float* __restrict__ out)
{
    const int batch = blockIdx.y, row = blockIdx.x, tid = threadIdx.x;
    const h4v* prow = (const h4v*)(P + ((size_t)batch * LDIM + row) * LDIM);
    const float4* b4 = (const float4*)(bv + batch * VS);
    const float4* c4 = (const float4*)(Cvec + batch * VS);
    const float4* m4 = (const float4*)(colM + batch * VS);
    const float Rr = Rvec[batch * VS + row];
    const float rM = rowM[batch * VS + row];
    const float as = av3[batch * VS + row];

    const size_t PLANE = (size_t)BDIM * LDIM * LDIM;
    const size_t base = ((size_t)batch * LDIM + row) * LDIM;
    for (int jv = tid; jv < 900; jv += 256) {
        h4v hv = prow[jv]; float4 b = b4[jv]; float4 c = c4[jv]; float4 cM = m4[jv];
        float4 cmv, cfv, skv;
        {
            float p = (float)hv[0]; float cm = (p * p) / (Rr * c.x);
            cmv.x = cm; cfv.x = (cm == rM && cm == cM.x) ? cm : 0.f; skv.x = p * as * b.x;
        }
        {
            float p = (float)hv[1]; float cm = (p * p) / (Rr * c.y);
            cmv.y = cm; cfv.y = (cm == rM && cm == cM.y) ? cm : 0.f; skv.y = p * as * b.y;
        }
        {
            float p = (float)hv[2]; float cm = (p * p) / (Rr * c.z);
            cmv.z = cm; cfv.z = (cm == rM && cm == cM.z) ? cm : 0.f; skv.z = p * as * b.z;
        }
        {
            float p = (float)hv[3]; float cm = (p * p) / (Rr * c.w);
            cmv.w = cm; cfv.w = (cm == rM && cm == cM.w) ? cm : 0.f; skv.w = p * as * b.w;
        }
        *(float4*)(out + base + jv * 4) = cmv;
        *(float4*)(out + PLANE + base + jv * 4) = cfv;
        *(float4*)(out + 2 * PLANE + base + jv * 4) = skv;
    }
}

extern "C" void kernel_launch(void* const* d_in, const int* in_sizes, int n_in,
                              void* d_out, int out_size, void* d_ws, size_t ws_size,
                              hipStream_t stream)
{
    const float* m0 = (const float*)d_in[0];
    const float* m1 = (const float*)d_in[1];
    const float* alpha = (const float*)d_in[2];
    float* out = (float*)d_out;
    char* ws = (char*)d_ws;

    // ws layout: bf16 inputs + fp16 P + small vectors (~59.4 MB total)
    short* Qb = (short*)(ws);                       // 3,686,400 B
    short* Rb = (short*)(ws + 3686400);             // 3,686,400 B
    _Float16* P = (_Float16*)(ws + 7372800);        // 51,840,000 B
    float* vec  = (float*)(ws + 59212800);
    float* sQ   = vec;                              // [2*256]  (memset)
    float* sR   = vec + 512;                        // [2*256]  (memset)
    float* rowM = vec + 1024;                       // [2*VS]   (zeroed by vectors)
    float* colM = rowM + 2 * VS;                    // [2*VS]   (zeroed by vectors)
    float* Rv   = colM + 2 * VS;                    // [2*VS]
    float* Cv   = Rv + 2 * VS;                      // [2*VS]
    float* bv   = Cv + 2 * VS;                      // [2*VS]
    float* av3  = bv + 2 * VS;                      // [2*VS]

    // node 1: zero sQ/sR only (4 KB)
    hipMemsetAsync(sQ, 0, 1024 * sizeof(float), stream);
    // node 2: convert + fused column sums
    convert_kernel<<<450, 256, 0, stream>>>((const float4*)m0, (const float4*)m1,
                                            (short4*)Qb, (short4*)Rb, sQ, sR);
    // node 3: per-row dots + closed-form Sinkhorn chain -> Rv,Cv,bv,av3 (+zero maxes)
    vectors_kernel<<<dim3(57, 2, 2), 256, 0, stream>>>(Qb, Rb, sQ, sR, alpha,
                                                       Rv, Cv, av3, bv, rowM, colM);
    // node 4: GEMM -> fp16 P + rowM/colM maxes
    expP_gemm_kernel<<<dim3(29, 29, 2), 256, 0, stream>>>(Qb, Rb, Rv, Cv, P, rowM, colM);
    // node 5: elementwise output planes
    final_kernel<<<dim3(3600, 2), 256, 0, stream>>>(P, bv, Rv, Cv, rowM, colM, av3, out);
}